// Round 2
// baseline (105.590 us; speedup 1.0000x reference)
//
#include <hip/hip_runtime.h>

// ExactAttention: block-diagonal masked softmax(Q K^T / sqrt(d)) @ V
// N=12288, D=128, 32 sorted batch segments, fp32 in/out.
// Global-max/EPS deviation ~1e-8 relative -> plain masked softmax.
//
// R12: ONE kernel, ZERO workspace. The prep kernel (12.6 MB fp32 read +
// 6.3 MB bf16 write + launch) existed only to feed global_load_lds; here
// each WG stages its own fp32 K/V tiles -> bf16 LDS in-register:
//   - K: row-major dwordx4 loads (coalesced), XOR-swizzle m^(row&15) --
//     LDS layout byte-identical to R11, MFMA read path unchanged.
//   - V: column gather (lane=d, 16 strided-but-wave-coalesced row reads),
//     swizzle re-derived as m^((d>>1)&3) so by-d register writes spread
//     bank quads evenly (old d&3 gave 16-way write aliasing).
//   - tile t+1 loads issue after barrier A, drain at barrier B -> hidden
//     under MFMA (same hiding point as R11's DMA).
// Segment bounds via 512-wide parallel window scan + LDS atomicMin
// (binary-search fallback for pathological segments); masking by
// seg-equality (fallback-proven). K/V tile-row indices clamp to NN-1:
// mask uses indices not data, so clamped garbage never contributes.
// In-WG split-K=2 + fp32 LDS merge kept from R11. NO device-scope fences.
// Net HBM: 37.8 -> 25.2 MB; kernel count 2 -> 1.

#define NN 12288
#define DD 128
#define PS_LD 40

typedef __attribute__((ext_vector_type(8))) short short8;
typedef __attribute__((ext_vector_type(4))) float float4v;

__device__ __forceinline__ short f2bf(float f) {
  unsigned u = __builtin_bit_cast(unsigned, f);
  return (short)((u + 0x7FFFu + ((u >> 16) & 1u)) >> 16);
}

__device__ __forceinline__ short8 ld8_bf16(const float* p) {
  float4v f0 = *(const float4v*)p;
  float4v f1 = *(const float4v*)(p + 4);
  short8 s;
  s[0] = f2bf(f0[0]); s[1] = f2bf(f0[1]); s[2] = f2bf(f0[2]); s[3] = f2bf(f0[3]);
  s[4] = f2bf(f1[0]); s[5] = f2bf(f1[1]); s[6] = f2bf(f1[2]); s[7] = f2bf(f1[3]);
  return s;
}

// SMEM carve (shorts):
//   [0,8192)      Ksh[2 splits][32 rows * 128]   (16 KB)
//   [8192,16384)  Vsh[2 splits][128 d * 32]      (16 KB)
//   [16384,21504) Ps[8 waves][16 * PS_LD]        (10 KB)
//   [21504,21512) LH (2 ints)
// Merge scratch reuses [0,16384) as 8192 fp32 and Ps region as Lf.
#define SM_V 8192
#define SM_PS 16384
#define SM_LH 21504

// issue tile loads into named registers (kA..kD = K 16 f32, vv = V 16 f32)
#define ISSUE_LOADS(J0)                                                   \
  {                                                                       \
    const int kr_ = min((J0) + krow, NN - 1);                             \
    const float* kp_ = K + (size_t)kr_ * DD + kch * 16;                   \
    kA = *(const float4v*)kp_;      kB = *(const float4v*)(kp_ + 4);      \
    kC = *(const float4v*)(kp_ + 8); kD = *(const float4v*)(kp_ + 12);    \
    _Pragma("unroll")                                                     \
    for (int j_ = 0; j_ < 16; ++j_) {                                     \
      const int vr_ = min((J0) + vkh * 16 + j_, NN - 1);                  \
      vv[j_] = V[(size_t)vr_ * DD + vd];                                  \
    }                                                                     \
  }

// convert staged registers -> bf16, write swizzled LDS tile
#define WRITE_LDS()                                                       \
  {                                                                       \
    short8 s0_, s1_;                                                      \
    s0_[0] = f2bf(kA[0]); s0_[1] = f2bf(kA[1]);                           \
    s0_[2] = f2bf(kA[2]); s0_[3] = f2bf(kA[3]);                           \
    s0_[4] = f2bf(kB[0]); s0_[5] = f2bf(kB[1]);                           \
    s0_[6] = f2bf(kB[2]); s0_[7] = f2bf(kB[3]);                           \
    s1_[0] = f2bf(kC[0]); s1_[1] = f2bf(kC[1]);                           \
    s1_[2] = f2bf(kC[2]); s1_[3] = f2bf(kC[3]);                           \
    s1_[4] = f2bf(kD[0]); s1_[5] = f2bf(kD[1]);                           \
    s1_[6] = f2bf(kD[2]); s1_[7] = f2bf(kD[3]);                           \
    *(short8*)(KshS + krow * 128 + kwp0) = s0_;                           \
    *(short8*)(KshS + krow * 128 + kwp1) = s1_;                           \
    short8 v0_, v1_;                                                      \
    _Pragma("unroll")                                                     \
    for (int j_ = 0; j_ < 8; ++j_) {                                      \
      v0_[j_] = f2bf(vv[j_]); v1_[j_] = f2bf(vv[8 + j_]);                 \
    }                                                                     \
    *(short8*)(VshS + vd * 32 + vwp0) = v0_;                              \
    *(short8*)(VshS + vd * 32 + vwp1) = v1_;                              \
  }

__global__ __launch_bounds__(512, 2) void attn_one(
    const float* __restrict__ Q, const float* __restrict__ K,
    const float* __restrict__ V, const int* __restrict__ seg,
    float* __restrict__ out) {
  __shared__ __align__(16) short SMEM[21512];

  const int tid = threadIdx.x;
  const int w = tid >> 6;
  const int lane = tid & 63;
  const int s = w & 1;        // key-split index
  const int r = w >> 1;       // row-wave (16 rows each)
  const int c = lane & 15;
  const int quad = lane >> 4;
  const int u = r * 64 + lane;  // split-local thread id 0..255

  // XCD x owns 24 contiguous row-groups (L2 reuse of its segments' K/V)
  const int bid = blockIdx.x;
  const int rg = (bid & 7) * 24 + (bid >> 3);
  const int i0 = rg * 64;
  const int i0w = i0 + r * 16;

  int* LH = (int*)(SMEM + SM_LH);
  if (tid == 0) { LH[0] = 0x7FFFFFFF; LH[1] = 0x7FFFFFFF; }

  // independent loads first (overlap the LH scan latency)
  short8 qf[4];
  {
    const float* qrow = Q + (size_t)(i0w + c) * DD + quad * 8;
#pragma unroll
    for (int kc = 0; kc < 4; ++kc) qf[kc] = ld8_bf16(qrow + kc * 32);
  }
  int seg_r[4];
#pragma unroll
  for (int rr = 0; rr < 4; ++rr) seg_r[rr] = seg[i0w + quad * 4 + rr];
  const int sFirst = seg[i0];
  const int sLast = seg[i0 + 63];
  __syncthreads();  // LH init visible

  // parallel boundary scan: L = first j with seg[j] >= sFirst (window of
  // 2048 ending at i0); H = first j >= i0+64 with seg[j] > sLast.
  {
    int locL = 0x7FFFFFFF, locH = 0x7FFFFFFF;
    const int ws0 = max(0, (i0 - 2040) & ~3);
#pragma unroll
    for (int j = 0; j < 4; ++j) {
      int p = ws0 + tid * 4 + j;
      if (p < NN && seg[p] >= sFirst) locL = min(locL, p);
      int q = i0 + 64 + tid * 4 + j;
      if (q < NN && seg[q] > sLast) locH = min(locH, q);
    }
#pragma unroll
    for (int m = 1; m < 64; m <<= 1) {
      locL = min(locL, __shfl_xor(locL, m, 64));
      locH = min(locH, __shfl_xor(locH, m, 64));
    }
    if (lane == 0) {
      atomicMin(&LH[0], locL);
      atomicMin(&LH[1], locH);
    }
  }
  __syncthreads();
  if (tid == 0) {  // pathological-segment fallback (never taken in practice)
    int Lc = LH[0];
    if (Lc > 0 && seg[Lc - 1] >= sFirst) {
      int lo = 0, hb = Lc;
      while (lo < hb) { int mid = (lo + hb) >> 1; if (seg[mid] < sFirst) lo = mid + 1; else hb = mid; }
      LH[0] = lo;
    }
    if (LH[1] == 0x7FFFFFFF) {
      if (i0 + 64 + 2048 >= NN) LH[1] = NN;
      else {
        int lo = i0 + 64, hb = NN;
        while (lo < hb) { int mid = (lo + hb) >> 1; if (seg[mid] <= sLast) lo = mid + 1; else hb = mid; }
        LH[1] = lo;
      }
    }
  }
  __syncthreads();
  const int L = LH[0], H = LH[1];

  const int Lm = L & ~31;
  const int nck = (H - Lm + 31) >> 5;
  const int ck0 = s ? (nck >> 1) : 0;
  const int nt  = s ? (nck - (nck >> 1)) : (nck >> 1);
  const int ntmax = nck - (nck >> 1);   // uniform loop count across WG

  // staging maps (per split: 256 threads stage one 32-key K tile + V tile)
  const int krow = u >> 3, kch = u & 7;            // K: row, 16-f32 chunk
  const int vd = u & 127, vkh = u >> 7;            // V: d column, key half
  short* KshS = SMEM + s * 4096;
  short* VshS = SMEM + SM_V + s * 4096;
  const int kwp0 = ((2 * kch)     ^ (krow & 15)) * 8;
  const int kwp1 = ((2 * kch + 1) ^ (krow & 15)) * 8;
  const int vsg = (vd >> 1) & 3;
  const int vwp0 = ((2 * vkh)     ^ vsg) * 8;
  const int vwp1 = ((2 * vkh + 1) ^ vsg) * 8;

  float4v kA, kB, kC, kD;
  float vv[16];

  float4v acc[8];
#pragma unroll
  for (int n = 0; n < 8; ++n) acc[n] = (float4v){0.f, 0.f, 0.f, 0.f};
  float l_part[4] = {0.f, 0.f, 0.f, 0.f};
  const float scale = 0.08838834764831845f;  // 1/sqrt(128)

  if (nt > 0) ISSUE_LOADS(Lm + ck0 * 32);

  for (int t = 0; t < ntmax; ++t) {
    const int j0 = Lm + (ck0 + t) * 32;
    if (t < nt) WRITE_LDS();     // regs(t) -> bf16 LDS (waits loads via use)
    __syncthreads();             // A: LDS tile ready (no vmem in flight here)
    if (t + 1 < nt) ISSUE_LOADS(j0 + 32);  // drained at B -> hidden by MFMA

    if (t < nt) {
      // --- S = Q K^T (16 rows x 32 keys), K from swizzled LDS ---
      float4v sa = (float4v){0.f, 0.f, 0.f, 0.f};
      float4v sb = (float4v){0.f, 0.f, 0.f, 0.f};
#pragma unroll
      for (int kc = 0; kc < 4; ++kc) {
        const int pos = ((kc * 4 + quad) ^ c) * 8;
        short8 b0 = *(const short8*)(KshS + c * 128 + pos);         // key j0+c
        short8 b1 = *(const short8*)(KshS + (16 + c) * 128 + pos);  // key j0+16+c
        sa = __builtin_amdgcn_mfma_f32_16x16x32_bf16(qf[kc], b0, sa, 0, 0, 0);
        sb = __builtin_amdgcn_mfma_f32_16x16x32_bf16(qf[kc], b1, sb, 0, 0, 0);
      }

      // --- mask (seg equality), exp, l partials, P -> LDS (C->A layout) ---
      const int ja = j0 + c, jb = ja + 16;
      const int sa2 = seg[ja < NN ? ja : NN - 1];
      const int sb2 = seg[jb < NN ? jb : NN - 1];
      const bool va = ja < NN, vb = jb < NN;
      short* prow = SMEM + SM_PS + w * (16 * PS_LD);
#pragma unroll
      for (int rr = 0; rr < 4; ++rr) {
        float pa = (va && sa2 == seg_r[rr]) ? __expf(sa[rr] * scale) : 0.f;
        float pb = (vb && sb2 == seg_r[rr]) ? __expf(sb[rr] * scale) : 0.f;
        l_part[rr] += pa + pb;
        int row = quad * 4 + rr;
        prow[row * PS_LD + c]      = f2bf(pa);
        prow[row * PS_LD + 16 + c] = f2bf(pb);
      }
      short8 pf = *(const short8*)(prow + c * PS_LD + quad * 8);

      // --- O += P V, swizzled V^T from LDS ---
      const int vpos = (quad ^ ((c >> 1) & 3)) * 8;
#pragma unroll
      for (int n = 0; n < 8; ++n) {
        short8 vf = *(const short8*)(VshS + (n * 16 + c) * 32 + vpos);
        acc[n] = __builtin_amdgcn_mfma_f32_16x16x32_bf16(pf, vf, acc[n], 0, 0, 0);
      }
    }

    __syncthreads();  // B: drains next-tile loads + LDS reads before overwrite
  }

  // ---- fp32 merge of the two splits via LDS (tile buffers are dead) ----
  float* Mf = reinterpret_cast<float*>(SMEM);           // 8192 floats
  float* Lf = reinterpret_cast<float*>(SMEM + SM_PS);   // 1024 floats used
  const int ml = r * 64 + lane;
  if (s == 1) {
#pragma unroll
    for (int n = 0; n < 8; ++n)
      *(float4v*)(Mf + n * 1024 + ml * 4) = acc[n];     // [n][lane] layout
#pragma unroll
    for (int rr = 0; rr < 4; ++rr) Lf[rr * 256 + ml] = l_part[rr];
  }
  __syncthreads();
  if (s == 0) {
#pragma unroll
    for (int n = 0; n < 8; ++n)
      acc[n] += *(const float4v*)(Mf + n * 1024 + ml * 4);

    float inv_r[4];
#pragma unroll
    for (int rr = 0; rr < 4; ++rr) {
      float l = l_part[rr] + Lf[rr * 256 + ml];
      l += __shfl_xor(l, 1, 64);
      l += __shfl_xor(l, 2, 64);
      l += __shfl_xor(l, 4, 64);
      l += __shfl_xor(l, 8, 64);
      inv_r[rr] = 1.f / (l + 1e-8f);
    }
#pragma unroll
    for (int n = 0; n < 8; ++n)
#pragma unroll
      for (int rr = 0; rr < 4; ++rr)
        out[(size_t)(i0w + quad * 4 + rr) * DD + n * 16 + c] = acc[n][rr] * inv_r[rr];
  }
}

extern "C" void kernel_launch(void* const* d_in, const int* in_sizes, int n_in,
                              void* d_out, int out_size, void* d_ws, size_t ws_size,
                              hipStream_t stream) {
  const float* Q = (const float*)d_in[0];
  const float* K = (const float*)d_in[1];
  const float* V = (const float*)d_in[2];
  const int* seg = (const int*)d_in[4];
  float* out = (float*)d_out;
  (void)d_ws; (void)ws_size;  // no workspace: single fused kernel

  attn_one<<<192, 512, 0, stream>>>(Q, K, V, seg, out);
}

// Round 3
// 93.717 us; speedup vs baseline: 1.1267x; 1.1267x over previous
//
#include <hip/hip_runtime.h>

// ExactAttention: block-diagonal masked softmax(Q K^T / sqrt(d)) @ V
// N=12288, D=128, 32 sorted batch segments, fp32 in/out.
// Global-max/EPS deviation ~1e-8 relative -> plain masked softmax.
//
// R13 = R11 (prep -> fused DMA-pipelined attn with in-WG split-K) with the
// attention workgroup halved for occupancy: 256 thr (2 row-waves x 2 key-
// splits), 32 rows/WG -> 384 WGs, LDS 69 KB -> 2 WGs/CU capacity. R12's
// register-staged variant was latency-bound (MfmaUtil 2.4%, occ 9.6%,
// 21-40us) -> reverted to the proven global_load_lds DMA path. With 192
// WGs of 512 thr, 64 CUs sat idle and each barrier's vmcnt(0) drain had
// no co-resident WG to hide under; 384 WGs fixes both. All swizzles, LDS
// read paths, merge and prep identical to verified R11.
// NO device-scope fences anywhere (R8: +125us from cross-XCD writeback).

#define NN 12288
#define DD 128
#define NB 32
#define PS_LD 40

typedef __attribute__((ext_vector_type(8))) short short8;
typedef __attribute__((ext_vector_type(4))) float float4v;

__device__ __forceinline__ short f2bf(float f) {
  unsigned u = __builtin_bit_cast(unsigned, f);
  return (short)((u + 0x7FFFu + ((u >> 16) & 1u)) >> 16);
}

__device__ __forceinline__ float bf2f(short s) {
  return __builtin_bit_cast(float, ((unsigned)(unsigned short)s) << 16);
}

__device__ __forceinline__ short8 ld8_bf16(const float* p) {
  float4v f0 = *(const float4v*)p;
  float4v f1 = *(const float4v*)(p + 4);
  short8 s;
  s[0] = f2bf(f0[0]); s[1] = f2bf(f0[1]); s[2] = f2bf(f0[2]); s[3] = f2bf(f0[3]);
  s[4] = f2bf(f1[0]); s[5] = f2bf(f1[1]); s[6] = f2bf(f1[2]); s[7] = f2bf(f1[3]);
  return s;
}

// async global->LDS DMA, 16B/lane: lds dest = uniform base + lane*16.
__device__ __forceinline__ void dma16(const short* gsrc, short* ldst) {
  auto g = (const __attribute__((address_space(1))) void*)(unsigned long long)gsrc;
  auto l = (__attribute__((address_space(3))) void*)(unsigned)(unsigned long long)ldst;
  __builtin_amdgcn_global_load_lds(g, l, 16, 0, 0);
}

// ---------- prep: Kb = bf16(K); Vt = tile-major pre-swizzled bf16 V^T;
// ---------- starts[] segment boundaries. 768 row-blocks + 48 starts-blocks.
// (verbatim from verified R11)
__global__ __launch_bounds__(256) void prep_kernel(
    const float* __restrict__ K, const float* __restrict__ V,
    const int* __restrict__ seg,
    short* __restrict__ Kb, short* __restrict__ Vt, int* __restrict__ starts) {
  const int tid = threadIdx.x;
  const int b = blockIdx.x;
  if (b < 768) {
    // XCD-aligned: block handles rows/keys r0..r0+15 with xcd = b&7
    const int r0 = ((b & 7) * 96 + (b >> 3)) * 16;
    // K cast: 16 rows x 128 = 2048 elems, 8 per thread, coalesced.
    const size_t base = (size_t)r0 * DD + (size_t)tid * 8;
    *(short8*)(Kb + base) = ld8_bf16(K + base);
    // V transpose-store: thread (d, kh) handles 8 consecutive keys at fixed d.
    const int d = tid & 127;
    const int k0 = r0 + (tid >> 7) * 8;
    short8 sv;
#pragma unroll
    for (int j = 0; j < 8; ++j) sv[j] = f2bf(V[(size_t)(k0 + j) * DD + d]);
    // dest: tile (k0>>5), d-row of 64B, 16B chunk m=(k0&31)>>3 stored at m^(d&3)
    const int m = (k0 & 31) >> 3;
    *(short8*)(Vt + (size_t)(k0 >> 5) * 4096 + d * 32 + ((m ^ (d & 3)) * 8)) = sv;
  } else {
    int i = (b - 768) * 256 + tid;
    int s = seg[i];
    int sp = (i == 0) ? -1 : seg[i - 1];
    for (int bb = sp + 1; bb <= s; ++bb) starts[bb] = i;
    if (i == NN - 1)
      for (int bb = s + 1; bb <= NB; ++bb) starts[bb] = NN;
  }
}

// issue one 32-key tile's DMAs for one row-wave half (4 K + 4 V instrs).
// Two waves per split stage the full 8KB K + 8KB V tile.
__device__ __forceinline__ void issue_tile(
    const short* __restrict__ Kb, const short* __restrict__ Vt,
    short* KshP, short* VshP, int j0, int wh, int lane) {
  // K tile: 32 rows x 256B, chunk m of row r stored at pos m^(r&15)
#pragma unroll
  for (int i = 0; i < 4; ++i) {
    const int R = wh * 16 + i * 4;           // 4 rows per instr
    const int row = R + (lane >> 4);
    const int dchunk = (lane & 15) ^ (row & 15);
    dma16(Kb + (size_t)(j0 + row) * DD + dchunk * 8, KshP + R * 128);
  }
  // V tile: contiguous pre-swizzled 8KB block; half wh copies 4KB.
  const size_t vbase = (size_t)(j0 >> 5) * 4096;
#pragma unroll
  for (int i = 0; i < 4; ++i) {
    const int off = (wh * 4 + i) * 512;      // shorts (1KB per instr)
    dma16(Vt + vbase + off + lane * 8, VshP + off);
  }
}

// ---------- fused attention: 256 thr = 2 row-waves x 2 key-splits,
// ---------- 32 rows/WG, DMA double-buffered, fp32 LDS merge -------------
__global__ __launch_bounds__(256, 2) void attn_fused(
    const float* __restrict__ Q, const short* __restrict__ Kb,
    const short* __restrict__ Vt, const int* __restrict__ seg,
    const int* __restrict__ starts, float* __restrict__ out) {
  __shared__ __align__(16) short Ksh[2][2][32 * 128];  // [split][dbuf] 32 KB
  __shared__ __align__(16) short Vsh[2][2][128 * 32];  // [split][dbuf] 32 KB
  __shared__ __align__(16) short Ps[4][16 * PS_LD];    // per-wave P    5 KB

  const int tid = threadIdx.x;
  const int w = tid >> 6;
  const int lane = tid & 63;
  const int s = w & 1;        // key-split index
  const int r = w >> 1;       // row-wave (16 rows each, 2 per WG)
  const int c = lane & 15;
  const int quad = lane >> 4;

  // XCD x owns 48 contiguous 32-row groups (matches prep placement)
  const int bid = blockIdx.x;
  const int rg = (bid & 7) * 48 + (bid >> 3);
  const int i0 = rg * 32;
  const int i0w = i0 + r * 16;

  // key range of this WG's 32 rows, halved across the two splits
  const int L = starts[seg[i0]];
  const int H = starts[seg[i0 + 31] + 1];
  const int Lm = L & ~31;
  const int nck = (H - Lm + 31) >> 5;
  const int ck0 = s ? (nck >> 1) : 0;
  const int nt  = s ? (nck - (nck >> 1)) : (nck >> 1);
  const int ntmax = nck - (nck >> 1);          // uniform loop count

  // per-row key ranges for masking
  int st_r[4], en_r[4];
#pragma unroll
  for (int rr = 0; rr < 4; ++rr) {
    int sv = seg[i0w + quad * 4 + rr];
    st_r[rr] = starts[sv];
    en_r[rr] = starts[sv + 1];
  }

  // resident Q A-frags for this wave's 16 rows
  short8 qf[4];
  {
    const float* qrow = Q + (size_t)(i0w + c) * DD + quad * 8;
#pragma unroll
    for (int kc = 0; kc < 4; ++kc) qf[kc] = ld8_bf16(qrow + kc * 32);
  }

  float4v acc[8];
#pragma unroll
  for (int n = 0; n < 8; ++n) acc[n] = (float4v){0.f, 0.f, 0.f, 0.f};
  float l_part[4] = {0.f, 0.f, 0.f, 0.f};

  const float scale = 0.08838834764831845f;   // 1/sqrt(128)

  if (nt > 0)
    issue_tile(Kb, Vt, &Ksh[s][0][0], &Vsh[s][0][0], Lm + ck0 * 32, r, lane);
  __syncthreads();   // drains tile-0 DMA (vmcnt(0) before s_barrier)

  for (int t = 0; t < ntmax; ++t) {
    const int p = t & 1;
    const int j0 = Lm + (ck0 + t) * 32;
    if (t + 1 < nt)
      issue_tile(Kb, Vt, &Ksh[s][p ^ 1][0], &Vsh[s][p ^ 1][0], j0 + 32, r, lane);

    if (t < nt) {
      // --- S = Q K^T (16 rows x 32 keys), K from swizzled LDS ---
      float4v sa = (float4v){0.f, 0.f, 0.f, 0.f};
      float4v sb = (float4v){0.f, 0.f, 0.f, 0.f};
      const short* Kp = &Ksh[s][p][0];
#pragma unroll
      for (int kc = 0; kc < 4; ++kc) {
        const int pos = ((kc * 4 + quad) ^ c) * 8;
        short8 b0 = *(const short8*)(Kp + c * 128 + pos);          // keys j0+c
        short8 b1 = *(const short8*)(Kp + (16 + c) * 128 + pos);   // keys j0+16+c
        sa = __builtin_amdgcn_mfma_f32_16x16x32_bf16(qf[kc], b0, sa, 0, 0, 0);
        sb = __builtin_amdgcn_mfma_f32_16x16x32_bf16(qf[kc], b1, sb, 0, 0, 0);
      }

      // --- mask (range compare), exp, l partials, P -> LDS (C->A layout) ---
      const int ja = j0 + c, jb = ja + 16;
      short* prow = &Ps[w][0];
#pragma unroll
      for (int rr = 0; rr < 4; ++rr) {
        float pa = (ja >= st_r[rr] && ja < en_r[rr]) ? __expf(sa[rr] * scale) : 0.f;
        float pb = (jb >= st_r[rr] && jb < en_r[rr]) ? __expf(sb[rr] * scale) : 0.f;
        l_part[rr] += pa + pb;
        int row = quad * 4 + rr;
        prow[row * PS_LD + c]      = f2bf(pa);
        prow[row * PS_LD + 16 + c] = f2bf(pb);
      }
      short8 pf = *(const short8*)&Ps[w][c * PS_LD + quad * 8];

      // --- O += P V, pre-swizzled V^T from LDS ---
      const short* Vp = &Vsh[s][p][0];
      const int vpos = (quad ^ (c & 3)) * 8;
#pragma unroll
      for (int n = 0; n < 8; ++n) {
        short8 vf = *(const short8*)(Vp + (n * 16 + c) * 32 + vpos);
        acc[n] = __builtin_amdgcn_mfma_f32_16x16x32_bf16(pf, vf, acc[n], 0, 0, 0);
      }
    }

    __syncthreads();  // drains next-tile DMA + all LDS reads before overwrite
  }

  // ---- fp32 merge of the two splits via LDS (tile buffers are dead) ----
  float* Mf = reinterpret_cast<float*>(&Ksh[0][0][0]);  // 8192 floats avail
  float* Lf = reinterpret_cast<float*>(&Vsh[0][0][0]);  // 512 floats used
  const int ml = r * 64 + lane;                          // 0..127
  if (s == 1) {
#pragma unroll
    for (int n = 0; n < 8; ++n)
      *(float4v*)(Mf + n * 512 + ml * 4) = acc[n];      // [n][lane] layout
#pragma unroll
    for (int rr = 0; rr < 4; ++rr) Lf[rr * 128 + ml] = l_part[rr];
  }
  __syncthreads();
  if (s == 0) {
#pragma unroll
    for (int n = 0; n < 8; ++n)
      acc[n] += *(const float4v*)(Mf + n * 512 + ml * 4);

    float inv_r[4];
#pragma unroll
    for (int rr = 0; rr < 4; ++rr) {
      float l = l_part[rr] + Lf[rr * 128 + ml];
      l += __shfl_xor(l, 1, 64);
      l += __shfl_xor(l, 2, 64);
      l += __shfl_xor(l, 4, 64);
      l += __shfl_xor(l, 8, 64);
      inv_r[rr] = 1.f / (l + 1e-8f);
    }
#pragma unroll
    for (int n = 0; n < 8; ++n)
#pragma unroll
      for (int rr = 0; rr < 4; ++rr)
        out[(size_t)(i0w + quad * 4 + rr) * DD + n * 16 + c] = acc[n][rr] * inv_r[rr];
  }
}

// ---------- fallback (verified R1 kernel) if ws_size is too small ----------
#define KT_LD 136
#define VT_LD 40
typedef __attribute__((ext_vector_type(4))) short short4v;

__global__ __launch_bounds__(256) void attn_fallback(
    const float* __restrict__ Q, const float* __restrict__ K,
    const float* __restrict__ V, const int* __restrict__ seg,
    float* __restrict__ out) {
  __shared__ __align__(16) short Kt[32 * KT_LD];
  __shared__ __align__(16) short Vtl[DD * VT_LD];
  __shared__ __align__(16) short Ps[4][16 * PS_LD];
  const int tid = threadIdx.x, wave = tid >> 6, lane = tid & 63;
  const int c = lane & 15, quad = lane >> 4;
  const int m0 = blockIdx.x * 64, i0 = m0 + wave * 16;
  const int segFirst = seg[m0], segLast = seg[m0 + 63];
  int lo = 0, hb = NN;
  while (lo < hb) { int mid = (lo + hb) >> 1; if (seg[mid] < segFirst) lo = mid + 1; else hb = mid; }
  int hi = lo, hb2 = NN;
  while (hi < hb2) { int mid = (hi + hb2) >> 1; if (seg[mid] <= segLast) hi = mid + 1; else hb2 = mid; }
  short8 qf[4];
  const float* qrow = Q + (size_t)(i0 + c) * DD + quad * 8;
#pragma unroll
  for (int kc = 0; kc < 4; ++kc) qf[kc] = ld8_bf16(qrow + kc * 32);
  int seg_r[4];
#pragma unroll
  for (int r = 0; r < 4; ++r) seg_r[r] = seg[i0 + quad * 4 + r];
  float4v acc[8];
#pragma unroll
  for (int n = 0; n < 8; ++n) acc[n] = (float4v){0.f, 0.f, 0.f, 0.f};
  float l_part[4] = {0.f, 0.f, 0.f, 0.f};
  const float scale = 0.08838834764831845f;
  for (int j0 = lo; j0 < hi; j0 += 32) {
    __syncthreads();
    {
      int row = tid >> 3, ch = tid & 7;
      int jj = j0 + row; if (jj > NN - 1) jj = NN - 1;
      const float* kp = K + (size_t)jj * DD + ch * 16;
      short* dst = &Kt[row * KT_LD + ch * 16];
#pragma unroll
      for (int q4 = 0; q4 < 4; ++q4) {
        float4v f = *(const float4v*)(kp + q4 * 4);
        short4v sx;
        sx[0] = f2bf(f[0]); sx[1] = f2bf(f[1]); sx[2] = f2bf(f[2]); sx[3] = f2bf(f[3]);
        *(short4v*)(dst + q4 * 4) = sx;
      }
    }
    {
      int d = tid & 127, jh = tid >> 7;
      float vv[16];
#pragma unroll
      for (int j = 0; j < 16; ++j) {
        int jj = j0 + jh * 16 + j; if (jj > NN - 1) jj = NN - 1;
        vv[j] = V[(size_t)jj * DD + d];
      }
      short8 a, b2;
#pragma unroll
      for (int j = 0; j < 8; ++j) { a[j] = f2bf(vv[j]); b2[j] = f2bf(vv[8 + j]); }
      *(short8*)&Vtl[d * VT_LD + jh * 16] = a;
      *(short8*)&Vtl[d * VT_LD + jh * 16 + 8] = b2;
    }
    __syncthreads();
    float4v sa = (float4v){0.f, 0.f, 0.f, 0.f};
    float4v sb = (float4v){0.f, 0.f, 0.f, 0.f};
    const short* krow0 = &Kt[c * KT_LD + quad * 8];
    const short* krow1 = &Kt[(16 + c) * KT_LD + quad * 8];
#pragma unroll
    for (int kc = 0; kc < 4; ++kc) {
      short8 b0 = *(const short8*)(krow0 + kc * 32);
      short8 b1 = *(const short8*)(krow1 + kc * 32);
      sa = __builtin_amdgcn_mfma_f32_16x16x32_bf16(qf[kc], b0, sa, 0, 0, 0);
      sb = __builtin_amdgcn_mfma_f32_16x16x32_bf16(qf[kc], b1, sb, 0, 0, 0);
    }
    int ja = j0 + c, jb = ja + 16;
    int sa2 = seg[ja < NN ? ja : NN - 1];
    int sb2 = seg[jb < NN ? jb : NN - 1];
    bool va = ja < hi, vb = jb < hi;
    short* prow = &Ps[wave][0];
#pragma unroll
    for (int r = 0; r < 4; ++r) {
      float pa = (va && sa2 == seg_r[r]) ? __expf(sa[r] * scale) : 0.f;
      float pb = (vb && sb2 == seg_r[r]) ? __expf(sb[r] * scale) : 0.f;
      l_part[r] += pa + pb;
      int row = quad * 4 + r;
      prow[row * PS_LD + c] = f2bf(pa);
      prow[row * PS_LD + 16 + c] = f2bf(pb);
    }
    short8 pf = *(const short8*)&Ps[wave][c * PS_LD + quad * 8];
#pragma unroll
    for (int n = 0; n < 8; ++n) {
      short8 vfr = *(const short8*)&Vtl[(n * 16 + c) * VT_LD + quad * 8];
      acc[n] = __builtin_amdgcn_mfma_f32_16x16x32_bf16(pf, vfr, acc[n], 0, 0, 0);
    }
  }
  float linv[4];
#pragma unroll
  for (int r = 0; r < 4; ++r) {
    float l = l_part[r];
    l += __shfl_xor(l, 1, 64);
    l += __shfl_xor(l, 2, 64);
    l += __shfl_xor(l, 4, 64);
    l += __shfl_xor(l, 8, 64);
    linv[r] = 1.f / (l + 1e-8f);
  }
#pragma unroll
  for (int n = 0; n < 8; ++n)
#pragma unroll
    for (int r = 0; r < 4; ++r)
      out[(size_t)(i0 + quad * 4 + r) * DD + n * 16 + c] = acc[n][r] * linv[r];
}

extern "C" void kernel_launch(void* const* d_in, const int* in_sizes, int n_in,
                              void* d_out, int out_size, void* d_ws, size_t ws_size,
                              hipStream_t stream) {
  const float* Q = (const float*)d_in[0];
  const float* K = (const float*)d_in[1];
  const float* V = (const float*)d_in[2];
  const int* seg = (const int*)d_in[4];
  float* out = (float*)d_out;

  const size_t kb_bytes = (size_t)NN * DD * sizeof(short);  // 3,145,728
  const size_t vt_bytes = (size_t)NN * DD * sizeof(short);  // 3,145,728
  const size_t st_bytes = 64 * sizeof(int);                 // 256
  const size_t need = kb_bytes + vt_bytes + st_bytes;

  if (ws_size >= need) {
    char* w = (char*)d_ws;
    short* Kb = (short*)w;      w += kb_bytes;
    short* Vt = (short*)w;      w += vt_bytes;
    int* starts = (int*)w;
    prep_kernel<<<768 + NN / 256, 256, 0, stream>>>(K, V, seg, Kb, Vt, starts);
    attn_fused<<<384, 256, 0, stream>>>(Q, Kb, Vt, seg, starts, out);
  } else {
    attn_fallback<<<NN / 64, 256, 0, stream>>>(Q, K, V, seg, out);
  }
}